// Round 3
// baseline (128.484 us; speedup 1.0000x reference)
//
#include <hip/hip_runtime.h>
#include <hip/hip_bf16.h>

#define ALPHA 0.2f

typedef unsigned short ushort_t;
typedef unsigned short ushort8 __attribute__((ext_vector_type(8)));
typedef float f32x4 __attribute__((ext_vector_type(4)));
typedef __bf16 bf16x8 __attribute__((ext_vector_type(8)));

// float -> bf16 bits, round-to-nearest-even (values are finite here)
__device__ __forceinline__ ushort_t f2bf(float f) {
  unsigned u = __float_as_uint(f);
  u += 0x7fffu + ((u >> 16) & 1u);
  return (ushort_t)(u >> 16);
}
__device__ __forceinline__ float bf2f(ushort_t b) {
  return __uint_as_float((unsigned)b << 16);
}

// ---------------------------------------------------------------------------
// Kernel A: h = X * W^T  (fp32), s1 = h.a1, s2 = h.a2 (fp32, from UNROUNDED h),
// and hT[b][d][n] in bf16 for the MFMA B-operand of kernel C.
// Block = 128 threads (thread == output channel d), 64 rows per block.
// ---------------------------------------------------------------------------
__global__ __launch_bounds__(128) void gat_h_kernel(
    const float* __restrict__ inp, const float* __restrict__ W,
    const float* __restrict__ avec, ushort_t* __restrict__ hT,
    float* __restrict__ s1, float* __restrict__ s2)
{
  const int b  = blockIdx.x >> 4;        // 16 chunks of 64 rows per batch
  const int n0 = (blockIdx.x & 15) << 6;
  const int t  = threadIdx.x;            // 0..127 == d

  __shared__ float    x_lds[64 * 64];    // 16 KB
  __shared__ ushort_t h_tile[128][72];   // 18 KB
  __shared__ float    s1p[2][64];
  __shared__ float    s2p[2][64];

  float wreg[64];
  {
    const float4* wrow = (const float4*)(W + t * 64);
#pragma unroll
    for (int k = 0; k < 16; ++k) {
      float4 v = wrow[k];
      wreg[4*k+0] = v.x; wreg[4*k+1] = v.y; wreg[4*k+2] = v.z; wreg[4*k+3] = v.w;
    }
  }
  const float a1 = avec[t];
  const float a2 = avec[128 + t];

  {
    const float4* xsrc = (const float4*)(inp + ((size_t)b * 1024 + n0) * 64);
    float4* xdst = (float4*)x_lds;
#pragma unroll
    for (int k = 0; k < 8; ++k) xdst[k * 128 + t] = xsrc[k * 128 + t];
  }
  __syncthreads();

  const int wv = t >> 6, ln = t & 63;
  for (int r = 0; r < 64; ++r) {
    const float4* xr = (const float4*)(x_lds + r * 64);
    float ax = 0.f, ay = 0.f, az = 0.f, aw = 0.f;
#pragma unroll
    for (int k = 0; k < 16; ++k) {
      float4 xv = xr[k];                  // broadcast ds_read_b128
      ax = fmaf(wreg[4*k+0], xv.x, ax);
      ay = fmaf(wreg[4*k+1], xv.y, ay);
      az = fmaf(wreg[4*k+2], xv.z, az);
      aw = fmaf(wreg[4*k+3], xv.w, aw);
    }
    const float h = (ax + ay) + (az + aw);
    h_tile[t][r] = f2bf(h);
    float v1 = h * a1, v2 = h * a2;      // fp32 scores from UNROUNDED h
#pragma unroll
    for (int m = 32; m >= 1; m >>= 1) {  // wave64 reduce
      v1 += __shfl_xor(v1, m);
      v2 += __shfl_xor(v2, m);
    }
    if (ln == 0) { s1p[wv][r] = v1; s2p[wv][r] = v2; }
  }
  __syncthreads();

  if (t < 64) {
    s1[(size_t)b * 1024 + n0 + t] = s1p[0][t] + s1p[1][t];
    s2[(size_t)b * 1024 + n0 + t] = s2p[0][t] + s2p[1][t];
  }

  // coalesced bf16 hT writes: 8 iters x (16 d-rows x 8 chunks of 16 B)
#pragma unroll
  for (int it = 0; it < 8; ++it) {
    const int d  = it * 16 + (t >> 3);
    const int ch = (t & 7) * 8;
    ushort8 v = *(const ushort8*)&h_tile[d][ch];
    *(ushort8*)(hT + ((size_t)b * 128 + d) * 1024 + n0 + ch) = v;
  }
}

// ---------------------------------------------------------------------------
// Kernel B: EXACT masked row max:  rm[b][i] = max_{j : graph[i][j] != 0} s2[b][j]
// Block = one graph row i (staged in LDS once); loop over the 32 batches.
// Guarantees den >= 1 in kernel C (argmax neighbor gets exp(0) = 1).
// ---------------------------------------------------------------------------
__global__ __launch_bounds__(256) void gat_rowmax_kernel(
    const float* __restrict__ graph, const float* __restrict__ s2,
    float* __restrict__ rm)
{
  const int i = blockIdx.x;      // 0..1023
  const int t = threadIdx.x;     // 0..255
  __shared__ float g_lds[1024];
  __shared__ float wpart[4];
  ((float4*)g_lds)[t] = ((const float4*)(graph + (size_t)i * 1024))[t];
  __syncthreads();
  const int w = t >> 6;
  for (int b = 0; b < 32; ++b) {
    float m = -1e30f;
#pragma unroll
    for (int k = 0; k < 4; ++k) {
      const int j = k * 256 + t;
      const float sv = s2[(size_t)b * 1024 + j];
      if (g_lds[j] != 0.f) m = fmaxf(m, sv);
    }
#pragma unroll
    for (int o = 32; o >= 1; o >>= 1) m = fmaxf(m, __shfl_xor(m, o));
    if ((t & 63) == 0) wpart[w] = m;
    __syncthreads();
    if (t == 0)
      rm[(size_t)b * 1024 + i] =
          fmaxf(fmaxf(wpart[0], wpart[1]), fmaxf(wpart[2], wpart[3]));
    __syncthreads();   // protect wpart before next batch overwrites
  }
}

// ---------------------------------------------------------------------------
// Kernel C: fused masked softmax + attention GEMM.
// Block = 256 threads (4 waves), tile = 64 i-rows x 128 d (full), j step 32.
// P tile computed in-register (fp32 logits, single pass via EXACT row max),
// written to LDS in the SAME k-permutation the MFMA A/B reads use
// (k = (lane>>4)*8+e)  =>  result independent of the HW k-layout.
// C/D layout: col = lane&15, row = (lane>>4)*4 + reg  [m89-verified].
// den accumulated from bf16-ROUNDED p so normalization cancels the systematic
// P-rounding scale error.
// ---------------------------------------------------------------------------
__global__ __launch_bounds__(256) void gat_attn_kernel(
    const float* __restrict__ graph, const ushort_t* __restrict__ hT,
    const float* __restrict__ s1g, const float* __restrict__ s2g,
    const float* __restrict__ rmg, const float* __restrict__ bias,
    float* __restrict__ out)
{
  const int ic = blockIdx.x;   // 0..15  (i-chunk fastest -> graph L2 locality)
  const int b  = blockIdx.y;   // 0..31
  const int i0 = ic << 6;
  const int t  = threadIdx.x;
  const int w  = t >> 6;
  const int l  = t & 63;

  __shared__ float    s2_lds[1024];      // 4 KB
  __shared__ ushort_t p_lds[64][32];     // 4 KB  (bf16 P tile)
  __shared__ ushort_t ht_lds[128][32];   // 8 KB  (bf16 h^T slab)
  __shared__ float    den_part[64][4];
  __shared__ float    den_row[64];

  {
    const float4* src = (const float4*)(s2g + (size_t)b * 1024);
    ((float4*)s2_lds)[t] = src[t];
  }
  const int irow = t >> 2;               // 0..63: P-row owned by this thread
  const int jsl  = (t & 3) * 8;          // its 8-wide j slot
  const float s1v = s1g[(size_t)b * 1024 + i0 + irow];
  const float rmx = rmg[(size_t)b * 1024 + i0 + irow];  // exact masked row max
  const float tm  = s1v + rmx;
  const float Mi  = tm > 0.f ? tm : ALPHA * tm;         // exact row max of lrelu
  const float* grow = graph + (size_t)(i0 + irow) * 1024 + jsl;
  const ushort_t* htb = hT + (size_t)b * 128 * 1024;

  float den_local = 0.f;
  f32x4 c[4][2];
#pragma unroll
  for (int is = 0; is < 4; ++is)
#pragma unroll
    for (int ds = 0; ds < 2; ++ds)
      c[is][ds] = f32x4{0.f, 0.f, 0.f, 0.f};
  __syncthreads();

  for (int jt = 0; jt < 32; ++jt) {
    const int j0 = jt * 32;
    // ---- phase 1: P tile (fp32 logits) + h^T slab staging ----
    float4 g0 = *(const float4*)(grow + j0);
    float4 g1 = *(const float4*)(grow + j0 + 4);
    float4 sA = *(const float4*)(s2_lds + j0 + jsl);
    float4 sB = *(const float4*)(s2_lds + j0 + jsl + 4);
    float gg[8] = {g0.x, g0.y, g0.z, g0.w, g1.x, g1.y, g1.z, g1.w};
    float ss[8] = {sA.x, sA.y, sA.z, sA.w, sB.x, sB.y, sB.z, sB.w};
    ushort8 pb;
#pragma unroll
    for (int e = 0; e < 8; ++e) {
      float te = s1v + ss[e];
      float v  = te > 0.f ? te : ALPHA * te;          // leaky relu
      // graph==0 or lrelu==0  ->  e = -1e16  ->  p = 0
      // masked entries never evaluate exp (their v may exceed Mi)
      float p  = (gg[e] != 0.f && v != 0.f) ? __expf(v - Mi) : 0.f;
      pb[e] = f2bf(p);
      den_local += bf2f(pb[e]);                        // den from ROUNDED p
    }
    *(ushort8*)&p_lds[irow][jsl] = pb;
#pragma unroll
    for (int k = 0; k < 2; ++k) {
      const int c2 = t + k * 256;
      const int d  = c2 >> 2;
      const int jc = (c2 & 3) * 8;
      *(ushort8*)&ht_lds[d][jc] =
          *(const ushort8*)(htb + (size_t)d * 1024 + j0 + jc);
    }
    __syncthreads();
    // ---- phase 2: MFMA (wave w owns d-range [32w, 32w+32)) ----
    bf16x8 av[4];
#pragma unroll
    for (int is = 0; is < 4; ++is)
      av[is] = __builtin_bit_cast(
          bf16x8, *(const ushort8*)&p_lds[is * 16 + (l & 15)][(l >> 4) * 8]);
#pragma unroll
    for (int ds = 0; ds < 2; ++ds) {
      bf16x8 bv = __builtin_bit_cast(
          bf16x8,
          *(const ushort8*)&ht_lds[w * 32 + ds * 16 + (l & 15)][(l >> 4) * 8]);
#pragma unroll
      for (int is = 0; is < 4; ++is)
        c[is][ds] =
            __builtin_amdgcn_mfma_f32_16x16x32_bf16(av[is], bv, c[is][ds], 0, 0, 0);
    }
    __syncthreads();
  }

  den_part[irow][t & 3] = den_local;
  __syncthreads();
  if (t < 64)
    den_row[t] = (den_part[t][0] + den_part[t][1]) +
                 (den_part[t][2] + den_part[t][3]);
  __syncthreads();

#pragma unroll
  for (int ds = 0; ds < 2; ++ds) {
    const int col = w * 32 + ds * 16 + (l & 15);
    const float bc = bias[col];
#pragma unroll
    for (int is = 0; is < 4; ++is) {
#pragma unroll
      for (int r = 0; r < 4; ++r) {
        const int row = is * 16 + (l >> 4) * 4 + r;
        const float dr = den_row[row];
        // dr >= 1 whenever the row has any neighbor; guard never emits NaN
        const float val = dr > 0.f ? c[is][ds][r] / dr + bc : bc;
        out[((size_t)b * 1024 + i0 + row) * 128 + col] = val;
      }
    }
  }
}

// ---------------------------------------------------------------------------
extern "C" void kernel_launch(void* const* d_in, const int* in_sizes, int n_in,
                              void* d_out, int out_size, void* d_ws, size_t ws_size,
                              hipStream_t stream) {
  (void)in_sizes; (void)n_in; (void)out_size; (void)ws_size;
  const float* inp   = (const float*)d_in[0];   // (32,1024,64) f32
  const float* graph = (const float*)d_in[1];   // (1024,1024)  f32
  const float* W     = (const float*)d_in[2];   // (128,64)     f32
  const float* bias  = (const float*)d_in[3];   // (128,)       f32
  const float* avec  = (const float*)d_in[4];   // (256,1)      f32
  float* out = (float*)d_out;                   // (32,1024,128) f32

  // workspace: hT bf16 8 MB | s1 128 KB | s2 128 KB | rowmax 128 KB
  ushort_t* hT = (ushort_t*)d_ws;
  float* s1 = (float*)((char*)d_ws + (size_t)32 * 128 * 1024 * 2);
  float* s2 = s1 + 32 * 1024;
  float* rm = s2 + 32 * 1024;

  gat_h_kernel<<<512, 128, 0, stream>>>(inp, W, avec, hT, s1, s2);
  gat_rowmax_kernel<<<1024, 256, 0, stream>>>(graph, s2, rm);
  gat_attn_kernel<<<dim3(16, 32), 256, 0, stream>>>(graph, hT, s1, s2, rm, bias, out);
}

// Round 6
// 90.657 us; speedup vs baseline: 1.4173x; 1.4173x over previous
//
#include <hip/hip_runtime.h>
#include <hip/hip_bf16.h>

#define ALPHA 0.2f

typedef unsigned short ushort_t;
typedef unsigned short ushort8 __attribute__((ext_vector_type(8)));
typedef float f32x4 __attribute__((ext_vector_type(4)));
typedef __bf16 bf16x8 __attribute__((ext_vector_type(8)));

// float -> bf16 bits, round-to-nearest-even (values are finite here)
__device__ __forceinline__ ushort_t f2bf(float f) {
  unsigned u = __float_as_uint(f);
  u += 0x7fffu + ((u >> 16) & 1u);
  return (ushort_t)(u >> 16);
}
__device__ __forceinline__ float bf2f(ushort_t b) {
  return __uint_as_float((unsigned)b << 16);
}

// ---------------------------------------------------------------------------
// Kernel A: h = X * W^T  (fp32), s1 = h.a1, s2 = h.a2 (fp32, from UNROUNDED h),
// and hT[b][d][n] in bf16 for the MFMA B-operand of kernel B.
// Block = 128 threads (thread == output channel d), 64 rows per block.
// ---------------------------------------------------------------------------
__global__ __launch_bounds__(128) void gat_h_kernel(
    const float* __restrict__ inp, const float* __restrict__ W,
    const float* __restrict__ avec, ushort_t* __restrict__ hT,
    float* __restrict__ s1, float* __restrict__ s2)
{
  const int b  = blockIdx.x >> 4;        // 16 chunks of 64 rows per batch
  const int n0 = (blockIdx.x & 15) << 6;
  const int t  = threadIdx.x;            // 0..127 == d

  __shared__ float    x_lds[64 * 64];    // 16 KB
  __shared__ ushort_t h_tile[128][72];   // 18 KB
  __shared__ float    s1p[2][64];
  __shared__ float    s2p[2][64];

  float wreg[64];
  {
    const float4* wrow = (const float4*)(W + t * 64);
#pragma unroll
    for (int k = 0; k < 16; ++k) {
      float4 v = wrow[k];
      wreg[4*k+0] = v.x; wreg[4*k+1] = v.y; wreg[4*k+2] = v.z; wreg[4*k+3] = v.w;
    }
  }
  const float a1 = avec[t];
  const float a2 = avec[128 + t];

  {
    const float4* xsrc = (const float4*)(inp + ((size_t)b * 1024 + n0) * 64);
    float4* xdst = (float4*)x_lds;
#pragma unroll
    for (int k = 0; k < 8; ++k) xdst[k * 128 + t] = xsrc[k * 128 + t];
  }
  __syncthreads();

  const int wv = t >> 6, ln = t & 63;
  for (int r = 0; r < 64; ++r) {
    const float4* xr = (const float4*)(x_lds + r * 64);
    float ax = 0.f, ay = 0.f, az = 0.f, aw = 0.f;
#pragma unroll
    for (int k = 0; k < 16; ++k) {
      float4 xv = xr[k];                  // broadcast ds_read_b128
      ax = fmaf(wreg[4*k+0], xv.x, ax);
      ay = fmaf(wreg[4*k+1], xv.y, ay);
      az = fmaf(wreg[4*k+2], xv.z, az);
      aw = fmaf(wreg[4*k+3], xv.w, aw);
    }
    const float h = (ax + ay) + (az + aw);
    h_tile[t][r] = f2bf(h);
    float v1 = h * a1, v2 = h * a2;      // fp32 scores from UNROUNDED h
#pragma unroll
    for (int m = 32; m >= 1; m >>= 1) {  // wave64 reduce
      v1 += __shfl_xor(v1, m);
      v2 += __shfl_xor(v2, m);
    }
    if (ln == 0) { s1p[wv][r] = v1; s2p[wv][r] = v2; }
  }
  __syncthreads();

  if (t < 64) {
    s1[(size_t)b * 1024 + n0 + t] = s1p[0][t] + s1p[1][t];
    s2[(size_t)b * 1024 + n0 + t] = s2p[0][t] + s2p[1][t];
  }

  // coalesced bf16 hT writes: 8 iters x (16 d-rows x 8 chunks of 16 B)
#pragma unroll
  for (int it = 0; it < 8; ++it) {
    const int d  = it * 16 + (t >> 3);
    const int ch = (t & 7) * 8;
    ushort8 v = *(const ushort8*)&h_tile[d][ch];
    *(ushort8*)(hT + ((size_t)b * 128 + d) * 1024 + n0 + ch) = v;
  }
}

// ---------------------------------------------------------------------------
// Kernel B: fused EXACT masked row max + softmax + attention GEMM.
// Block = 256 threads (4 waves), tile = 64 i-rows x 128 d (full), j step 32.
//
// Prepass: rm[i] = max_{j: g[i][j]!=0} s2[b][j], swept with the SAME access
// pattern as the main loop (warms L2) -> Mi = lrelu(s1+rm) is the exact row
// max -> den >= 1 always, no underflow possible.
//
// P tile written to LDS in the SAME k-permutation the MFMA A/B reads use
// (k = (lane>>4)*8+e)  =>  result independent of the HW k-layout.
// C/D layout: col = lane&15, row = (lane>>4)*4 + reg  [m89-verified].
// den accumulated from bf16-ROUNDED p so normalization cancels the systematic
// P-rounding scale error.
// ---------------------------------------------------------------------------
__global__ __launch_bounds__(256) void gat_attn_kernel(
    const float* __restrict__ graph, const ushort_t* __restrict__ hT,
    const float* __restrict__ s1g, const float* __restrict__ s2g,
    const float* __restrict__ bias, float* __restrict__ out)
{
  const int ic = blockIdx.x;   // 0..15  (ic fastest -> same-ic blocks share XCD L2)
  const int b  = blockIdx.y;   // 0..31
  const int i0 = ic << 6;
  const int t  = threadIdx.x;
  const int w  = t >> 6;
  const int l  = t & 63;

  __shared__ float    s2_lds[1024];      // 4 KB
  __shared__ ushort_t p_lds[64][32];     // 4 KB  (bf16 P tile)
  __shared__ ushort_t ht_lds[128][32];   // 8 KB  (bf16 h^T slab)
  __shared__ float    red_part[64][4];   // reused: rowmax prepass, then den
  __shared__ float    red_row[64];

  {
    const float4* src = (const float4*)(s2g + (size_t)b * 1024);
    ((float4*)s2_lds)[t] = src[t];
  }
  const int irow = t >> 2;               // 0..63: P-row owned by this thread
  const int jsl  = (t & 3) * 8;          // its 8-wide j slot
  const float s1v = s1g[(size_t)b * 1024 + i0 + irow];
  const float* grow = graph + (size_t)(i0 + irow) * 1024 + jsl;
  const ushort_t* htb = hT + ((size_t)b * 128 + irow) * 1024 + jsl;
  __syncthreads();                       // s2_lds ready

  // ---- prepass: exact masked row max (same addresses as main loop) ----
  float mx_local = -1e30f;
  for (int jt = 0; jt < 32; ++jt) {
    const int j0 = jt * 32;
    float4 g0 = *(const float4*)(grow + j0);
    float4 g1 = *(const float4*)(grow + j0 + 4);
    float4 sA = *(const float4*)(s2_lds + j0 + jsl);
    float4 sB = *(const float4*)(s2_lds + j0 + jsl + 4);
    if (g0.x != 0.f) mx_local = fmaxf(mx_local, sA.x);
    if (g0.y != 0.f) mx_local = fmaxf(mx_local, sA.y);
    if (g0.z != 0.f) mx_local = fmaxf(mx_local, sA.z);
    if (g0.w != 0.f) mx_local = fmaxf(mx_local, sA.w);
    if (g1.x != 0.f) mx_local = fmaxf(mx_local, sB.x);
    if (g1.y != 0.f) mx_local = fmaxf(mx_local, sB.y);
    if (g1.z != 0.f) mx_local = fmaxf(mx_local, sB.z);
    if (g1.w != 0.f) mx_local = fmaxf(mx_local, sB.w);
  }
  red_part[irow][t & 3] = mx_local;
  __syncthreads();
  if (t < 64)
    red_row[t] = fmaxf(fmaxf(red_part[t][0], red_part[t][1]),
                       fmaxf(red_part[t][2], red_part[t][3]));
  __syncthreads();
  const float tm = s1v + red_row[irow];
  const float Mi = tm > 0.f ? tm : ALPHA * tm;   // exact row max of lrelu
  __syncthreads();                                // red_* reused for den below

  float den_local = 0.f;
  f32x4 c[4][2];
#pragma unroll
  for (int is = 0; is < 4; ++is)
#pragma unroll
    for (int ds = 0; ds < 2; ++ds)
      c[is][ds] = f32x4{0.f, 0.f, 0.f, 0.f};

  for (int jt = 0; jt < 32; ++jt) {
    const int j0 = jt * 32;
    // ---- phase 1: issue global loads FIRST (latency hides under exp) ----
    ushort8 h0 = *(const ushort8*)(htb + j0);            // row irow
    ushort8 h1 = *(const ushort8*)(htb + 64 * 1024 + j0);// row irow+64
    float4 g0 = *(const float4*)(grow + j0);
    float4 g1 = *(const float4*)(grow + j0 + 4);
    float4 sA = *(const float4*)(s2_lds + j0 + jsl);
    float4 sB = *(const float4*)(s2_lds + j0 + jsl + 4);
    float gg[8] = {g0.x, g0.y, g0.z, g0.w, g1.x, g1.y, g1.z, g1.w};
    float ss[8] = {sA.x, sA.y, sA.z, sA.w, sB.x, sB.y, sB.z, sB.w};
    ushort8 pb;
#pragma unroll
    for (int e = 0; e < 8; ++e) {
      float te = s1v + ss[e];
      float v  = te > 0.f ? te : ALPHA * te;          // leaky relu
      // graph==0 or lrelu==0  ->  e = -1e16  ->  p = 0
      // masked entries never evaluate exp (their v may exceed Mi)
      float p  = (gg[e] != 0.f && v != 0.f) ? __expf(v - Mi) : 0.f;
      pb[e] = f2bf(p);
      den_local += bf2f(pb[e]);                        // den from ROUNDED p
    }
    *(ushort8*)&p_lds[irow][jsl] = pb;
    *(ushort8*)&ht_lds[irow][jsl] = h0;
    *(ushort8*)&ht_lds[irow + 64][jsl] = h1;
    __syncthreads();
    // ---- phase 2: MFMA (wave w owns d-range [32w, 32w+32)) ----
    bf16x8 av[4];
#pragma unroll
    for (int is = 0; is < 4; ++is)
      av[is] = __builtin_bit_cast(
          bf16x8, *(const ushort8*)&p_lds[is * 16 + (l & 15)][(l >> 4) * 8]);
#pragma unroll
    for (int ds = 0; ds < 2; ++ds) {
      bf16x8 bv = __builtin_bit_cast(
          bf16x8,
          *(const ushort8*)&ht_lds[w * 32 + ds * 16 + (l & 15)][(l >> 4) * 8]);
#pragma unroll
      for (int is = 0; is < 4; ++is)
        c[is][ds] =
            __builtin_amdgcn_mfma_f32_16x16x32_bf16(av[is], bv, c[is][ds], 0, 0, 0);
    }
    __syncthreads();
  }

  red_part[irow][t & 3] = den_local;
  __syncthreads();
  if (t < 64)
    red_row[t] = (red_part[t][0] + red_part[t][1]) +
                 (red_part[t][2] + red_part[t][3]);
  __syncthreads();

#pragma unroll
  for (int ds = 0; ds < 2; ++ds) {
    const int col = w * 32 + ds * 16 + (l & 15);
    const float bc = bias[col];
#pragma unroll
    for (int is = 0; is < 4; ++is) {
#pragma unroll
      for (int r = 0; r < 4; ++r) {
        const int row = is * 16 + (l >> 4) * 4 + r;
        const float dr = red_row[row];
        // dr >= 1 whenever the row has any neighbor; guard never emits NaN
        const float val = dr > 0.f ? c[is][ds][r] / dr + bc : bc;
        out[((size_t)b * 1024 + i0 + row) * 128 + col] = val;
      }
    }
  }
}

// ---------------------------------------------------------------------------
extern "C" void kernel_launch(void* const* d_in, const int* in_sizes, int n_in,
                              void* d_out, int out_size, void* d_ws, size_t ws_size,
                              hipStream_t stream) {
  (void)in_sizes; (void)n_in; (void)out_size; (void)ws_size;
  const float* inp   = (const float*)d_in[0];   // (32,1024,64) f32
  const float* graph = (const float*)d_in[1];   // (1024,1024)  f32
  const float* W     = (const float*)d_in[2];   // (128,64)     f32
  const float* bias  = (const float*)d_in[3];   // (128,)       f32
  const float* avec  = (const float*)d_in[4];   // (256,1)      f32
  float* out = (float*)d_out;                   // (32,1024,128) f32

  // workspace: hT bf16 8 MB | s1 128 KB | s2 128 KB
  ushort_t* hT = (ushort_t*)d_ws;
  float* s1 = (float*)((char*)d_ws + (size_t)32 * 128 * 1024 * 2);
  float* s2 = s1 + 32 * 1024;

  gat_h_kernel<<<512, 128, 0, stream>>>(inp, W, avec, hT, s1, s2);
  gat_attn_kernel<<<dim3(16, 32), 256, 0, stream>>>(graph, hT, s1, s2, bias, out);
}

// Round 7
// 67.090 us; speedup vs baseline: 1.9151x; 1.3513x over previous
//
#include <hip/hip_runtime.h>
#include <hip/hip_bf16.h>

#define ALPHA 0.2f

typedef unsigned short ushort_t;
typedef unsigned short ushort8 __attribute__((ext_vector_type(8)));
typedef float f32x4 __attribute__((ext_vector_type(4)));
typedef __bf16 bf16x8 __attribute__((ext_vector_type(8)));

// float -> bf16 bits, round-to-nearest-even (values are finite here)
__device__ __forceinline__ ushort_t f2bf(float f) {
  unsigned u = __float_as_uint(f);
  u += 0x7fffu + ((u >> 16) & 1u);
  return (ushort_t)(u >> 16);
}
__device__ __forceinline__ float bf2f(ushort_t b) {
  return __uint_as_float((unsigned)b << 16);
}

// ---------------------------------------------------------------------------
// Kernel A: h = X * W^T  (fp32), s1 = h.a1, s2 = h.a2 (fp32, from UNROUNDED h),
// and hT[b][d][n] in bf16 for the MFMA B-operand of kernel B.
// 32 rows/block (grid 1024) -> 4 blocks/CU for latency hiding.
// ---------------------------------------------------------------------------
__global__ __launch_bounds__(128) void gat_h_kernel(
    const float* __restrict__ inp, const float* __restrict__ W,
    const float* __restrict__ avec, ushort_t* __restrict__ hT,
    float* __restrict__ s1, float* __restrict__ s2)
{
  const int b  = blockIdx.x >> 5;        // 32 chunks of 32 rows per batch
  const int n0 = (blockIdx.x & 31) << 5;
  const int t  = threadIdx.x;            // 0..127 == d

  __shared__ float    x_lds[32 * 64];    // 8 KB
  __shared__ ushort_t h_tile[128][40];   // 10 KB (pad 32->40: 2-way banks max)
  __shared__ float    s1p[2][32];
  __shared__ float    s2p[2][32];

  float wreg[64];
  {
    const float4* wrow = (const float4*)(W + t * 64);
#pragma unroll
    for (int k = 0; k < 16; ++k) {
      float4 v = wrow[k];
      wreg[4*k+0] = v.x; wreg[4*k+1] = v.y; wreg[4*k+2] = v.z; wreg[4*k+3] = v.w;
    }
  }
  const float a1 = avec[t];
  const float a2 = avec[128 + t];

  {
    const float4* xsrc = (const float4*)(inp + ((size_t)b * 1024 + n0) * 64);
    float4* xdst = (float4*)x_lds;
#pragma unroll
    for (int k = 0; k < 4; ++k) xdst[k * 128 + t] = xsrc[k * 128 + t];
  }
  __syncthreads();

  const int wv = t >> 6, ln = t & 63;
  for (int r = 0; r < 32; ++r) {
    const float4* xr = (const float4*)(x_lds + r * 64);
    float ax = 0.f, ay = 0.f, az = 0.f, aw = 0.f;
#pragma unroll
    for (int k = 0; k < 16; ++k) {
      float4 xv = xr[k];                  // broadcast ds_read_b128
      ax = fmaf(wreg[4*k+0], xv.x, ax);
      ay = fmaf(wreg[4*k+1], xv.y, ay);
      az = fmaf(wreg[4*k+2], xv.z, az);
      aw = fmaf(wreg[4*k+3], xv.w, aw);
    }
    const float h = (ax + ay) + (az + aw);
    h_tile[t][r] = f2bf(h);
    float v1 = h * a1, v2 = h * a2;      // fp32 scores from UNROUNDED h
#pragma unroll
    for (int m = 32; m >= 1; m >>= 1) {  // wave64 reduce
      v1 += __shfl_xor(v1, m);
      v2 += __shfl_xor(v2, m);
    }
    if (ln == 0) { s1p[wv][r] = v1; s2p[wv][r] = v2; }
  }
  __syncthreads();

  if (t < 32) {
    s1[(size_t)b * 1024 + n0 + t] = s1p[0][t] + s1p[1][t];
    s2[(size_t)b * 1024 + n0 + t] = s2p[0][t] + s2p[1][t];
  }

  // coalesced bf16 hT writes: 4 iters x (32 d-rows x 4 chunks of 16 B)
#pragma unroll
  for (int it = 0; it < 4; ++it) {
    const int d  = it * 32 + (t >> 2);
    const int ch = (t & 3) * 8;
    ushort8 v = *(const ushort8*)&h_tile[d][ch];
    *(ushort8*)(hT + ((size_t)b * 128 + d) * 1024 + n0 + ch) = v;
  }
}

// ---------------------------------------------------------------------------
// Kernel B: fused EXACT masked row max + softmax + attention GEMM.
// Block = 256 threads (4 waves), tile = 32 i-rows x 128 d, j step 64.
// Grid (32 ic, 32 b) = 1024 blocks -> 4 blocks/CU (occupancy fix).
//
// Prepass: rm[i] = max_{j: g[i][j]!=0} s2[b][j]  ->  Mi = lrelu(s1+rm) is the
// exact row max -> den >= 1 always, no underflow possible.
//
// P written to LDS in the SAME k-permutation the MFMA A/B reads use
// (k = kk*32 + (lane>>4)*8 + e)  =>  result independent of the HW k-layout.
// C/D layout: col = lane&15, row = (lane>>4)*4 + reg  [m89-verified].
// LDS rows padded to 72 ushorts (144 B = 9x16B): b128-aligned, 2-way banks.
// den accumulated from bf16-ROUNDED p (cancels P-rounding scale error).
// ---------------------------------------------------------------------------
__global__ __launch_bounds__(256) void gat_attn_kernel(
    const float* __restrict__ graph, const ushort_t* __restrict__ hT,
    const float* __restrict__ s1g, const float* __restrict__ s2g,
    const float* __restrict__ bias, float* __restrict__ out)
{
  const int ic = blockIdx.x;   // 0..31  (ic fastest -> same-b blocks co-resident)
  const int b  = blockIdx.y;   // 0..31
  const int i0 = ic << 5;
  const int t  = threadIdx.x;
  const int w  = t >> 6;
  const int l  = t & 63;

  __shared__ float    s2_lds[1024];      // 4 KB
  __shared__ ushort_t p_lds[32][72];     // 4.5 KB (bf16 P tile, padded)
  __shared__ ushort_t ht_lds[128][72];   // 18 KB  (bf16 h^T slab, padded)
  __shared__ float    red_part[32][8];   // reused: rowmax prepass, then den
  __shared__ float    red_row[32];

  {
    const float4* src = (const float4*)(s2g + (size_t)b * 1024);
    ((float4*)s2_lds)[t] = src[t];
  }
  const int irow = t >> 3;               // 0..31: P-row owned by this thread
  const int jsl  = (t & 7) * 8;          // its 8-wide j slot within the 64-tile
  const float s1v = s1g[(size_t)b * 1024 + i0 + irow];
  const float* grow = graph + (size_t)(i0 + irow) * 1024 + jsl;
  const ushort_t* htb = hT + (size_t)b * 128 * 1024;
  __syncthreads();                       // s2_lds ready

  // ---- prepass: exact masked row max (same addresses as main loop) ----
  float mx_local = -1e30f;
  for (int jt = 0; jt < 16; ++jt) {
    const int j0 = jt * 64;
    float4 g0 = *(const float4*)(grow + j0);
    float4 g1 = *(const float4*)(grow + j0 + 4);
    float4 sA = *(const float4*)(s2_lds + j0 + jsl);
    float4 sB = *(const float4*)(s2_lds + j0 + jsl + 4);
    if (g0.x != 0.f) mx_local = fmaxf(mx_local, sA.x);
    if (g0.y != 0.f) mx_local = fmaxf(mx_local, sA.y);
    if (g0.z != 0.f) mx_local = fmaxf(mx_local, sA.z);
    if (g0.w != 0.f) mx_local = fmaxf(mx_local, sA.w);
    if (g1.x != 0.f) mx_local = fmaxf(mx_local, sB.x);
    if (g1.y != 0.f) mx_local = fmaxf(mx_local, sB.y);
    if (g1.z != 0.f) mx_local = fmaxf(mx_local, sB.z);
    if (g1.w != 0.f) mx_local = fmaxf(mx_local, sB.w);
  }
  red_part[irow][t & 7] = mx_local;
  __syncthreads();
  if (t < 32) {
    float m = red_part[t][0];
#pragma unroll
    for (int k = 1; k < 8; ++k) m = fmaxf(m, red_part[t][k]);
    red_row[t] = m;
  }
  __syncthreads();
  const float tm = s1v + red_row[irow];
  const float Mi = tm > 0.f ? tm : ALPHA * tm;   // exact row max of lrelu
  __syncthreads();                                // red_* reused for den below

  float den_local = 0.f;
  f32x4 c[2][2];
#pragma unroll
  for (int is = 0; is < 2; ++is)
#pragma unroll
    for (int ds = 0; ds < 2; ++ds)
      c[is][ds] = f32x4{0.f, 0.f, 0.f, 0.f};

  for (int jt = 0; jt < 16; ++jt) {
    const int j0 = jt * 64;
    // ---- phase 1: issue global loads FIRST (latency hides under exp) ----
    ushort8 hv[4];
#pragma unroll
    for (int k = 0; k < 4; ++k) {
      const int c2 = t + k * 256;
      const int d  = c2 >> 3;
      const int jc = (c2 & 7) * 8;
      hv[k] = *(const ushort8*)(htb + (size_t)d * 1024 + j0 + jc);
    }
    float4 g0 = *(const float4*)(grow + j0);
    float4 g1 = *(const float4*)(grow + j0 + 4);
    float4 sA = *(const float4*)(s2_lds + j0 + jsl);
    float4 sB = *(const float4*)(s2_lds + j0 + jsl + 4);
    float gg[8] = {g0.x, g0.y, g0.z, g0.w, g1.x, g1.y, g1.z, g1.w};
    float ss[8] = {sA.x, sA.y, sA.z, sA.w, sB.x, sB.y, sB.z, sB.w};
    ushort8 pb;
#pragma unroll
    for (int e = 0; e < 8; ++e) {
      float te = s1v + ss[e];
      float v  = te > 0.f ? te : ALPHA * te;          // leaky relu
      // graph==0 or lrelu==0  ->  e = -1e16  ->  p = 0
      // masked entries never evaluate exp (their v may exceed Mi)
      float p  = (gg[e] != 0.f && v != 0.f) ? __expf(v - Mi) : 0.f;
      pb[e] = f2bf(p);
      den_local += bf2f(pb[e]);                        // den from ROUNDED p
    }
    *(ushort8*)&p_lds[irow][jsl] = pb;
#pragma unroll
    for (int k = 0; k < 4; ++k) {
      const int c2 = t + k * 256;
      const int d  = c2 >> 3;
      const int jc = (c2 & 7) * 8;
      *(ushort8*)&ht_lds[d][jc] = hv[k];
    }
    __syncthreads();
    // ---- phase 2: MFMA (wave w owns d-range [32w, 32w+32)) ----
#pragma unroll
    for (int kk = 0; kk < 2; ++kk) {
      const int kcol = kk * 32 + (l >> 4) * 8;
      bf16x8 av[2];
#pragma unroll
      for (int is = 0; is < 2; ++is)
        av[is] = __builtin_bit_cast(
            bf16x8, *(const ushort8*)&p_lds[is * 16 + (l & 15)][kcol]);
#pragma unroll
      for (int ds = 0; ds < 2; ++ds) {
        bf16x8 bv = __builtin_bit_cast(
            bf16x8,
            *(const ushort8*)&ht_lds[w * 32 + ds * 16 + (l & 15)][kcol]);
#pragma unroll
        for (int is = 0; is < 2; ++is)
          c[is][ds] = __builtin_amdgcn_mfma_f32_16x16x32_bf16(
              av[is], bv, c[is][ds], 0, 0, 0);
      }
    }
    __syncthreads();
  }

  red_part[irow][t & 7] = den_local;
  __syncthreads();
  if (t < 32) {
    float s = red_part[t][0];
#pragma unroll
    for (int k = 1; k < 8; ++k) s += red_part[t][k];
    red_row[t] = s;
  }
  __syncthreads();

#pragma unroll
  for (int ds = 0; ds < 2; ++ds) {
    const int col = w * 32 + ds * 16 + (l & 15);
    const float bc = bias[col];
#pragma unroll
    for (int is = 0; is < 2; ++is) {
#pragma unroll
      for (int r = 0; r < 4; ++r) {
        const int row = is * 16 + (l >> 4) * 4 + r;
        const float dr = red_row[row];
        // dr >= 1 whenever the row has any neighbor; guard never emits NaN
        const float val = dr > 0.f ? c[is][ds][r] / dr + bc : bc;
        out[((size_t)b * 1024 + i0 + row) * 128 + col] = val;
      }
    }
  }
}

// ---------------------------------------------------------------------------
extern "C" void kernel_launch(void* const* d_in, const int* in_sizes, int n_in,
                              void* d_out, int out_size, void* d_ws, size_t ws_size,
                              hipStream_t stream) {
  (void)in_sizes; (void)n_in; (void)out_size; (void)ws_size;
  const float* inp   = (const float*)d_in[0];   // (32,1024,64) f32
  const float* graph = (const float*)d_in[1];   // (1024,1024)  f32
  const float* W     = (const float*)d_in[2];   // (128,64)     f32
  const float* bias  = (const float*)d_in[3];   // (128,)       f32
  const float* avec  = (const float*)d_in[4];   // (256,1)      f32
  float* out = (float*)d_out;                   // (32,1024,128) f32

  // workspace: hT bf16 8 MB | s1 128 KB | s2 128 KB
  ushort_t* hT = (ushort_t*)d_ws;
  float* s1 = (float*)((char*)d_ws + (size_t)32 * 128 * 1024 * 2);
  float* s2 = s1 + 32 * 1024;

  gat_h_kernel<<<1024, 128, 0, stream>>>(inp, W, avec, hT, s1, s2);
  gat_attn_kernel<<<dim3(32, 32), 256, 0, stream>>>(graph, hT, s1, s2, bias, out);
}